// Round 28
// baseline (141.046 us; speedup 1.0000x reference)
//
#include <hip/hip_runtime.h>

typedef __attribute__((ext_vector_type(8))) short bf16x8;
typedef __attribute__((ext_vector_type(4))) float f32x4;

constexpr int L  = 384;
constexpr int R  = 256;
constexpr int D  = 128;
constexpr int NH = 8;
constexpr int HD = 16;
constexpr int FF = 512;

constexpr int NTILE  = 48;                 // L/8
constexpr int NPAIRT = NTILE * (NTILE + 1) / 2;   // 1176 tile blocks

#define MFMA16(a, b, c) __builtin_amdgcn_mfma_f32_16x16x32_bf16((a), (b), (c), 0, 0, 0)

__device__ inline unsigned short f2bf(float f) {
    unsigned u = __builtin_bit_cast(unsigned, f);
    u += 0x7fffu + ((u >> 16) & 1u);          // round-to-nearest-even
    return (unsigned short)(u >> 16);
}
__device__ inline float bf2f(unsigned short h) {
    unsigned u = ((unsigned)h) << 16;
    return __builtin_bit_cast(float, u);
}

// ---------------------------------------------------------------------------
// Prep: attn weights (w1p/w2p), LN3-fold constants, FRAGMENTIZED FFN weights
// ---------------------------------------------------------------------------
__global__ void k_prep(const float* __restrict__ w1,
                       const float* __restrict__ w2,
                       const float* __restrict__ ffw1,
                       const float* __restrict__ ffw2,
                       const float* __restrict__ g3,
                       const float* __restrict__ b3,
                       const float* __restrict__ ffb1,
                       unsigned short* __restrict__ w1p,
                       unsigned short* __restrict__ w2p,
                       unsigned short* __restrict__ w1gF,
                       unsigned short* __restrict__ w2tF,
                       float2* __restrict__ c1c2) {
    const int idx = blockIdx.x * 256 + threadIdx.x;   // 65536 threads
    {
        const int fi = idx >> 9, rem = idx & 511, l = rem >> 3, e = rem & 7;
        const int lr2 = l & 15, lg2 = l >> 4;
        const int n = fi >> 2, ks = fi & 3;
        const int ch = n * 16 + lr2, k = ks * 32 + lg2 * 8 + e;
        w1gF[idx] = f2bf(g3[k] * ffw1[(size_t)k * FF + ch]);
    }
    {
        const int fi = idx >> 9, rem = idx & 511, l = rem >> 3, e = rem & 7;
        const int lr2 = l & 15, lg2 = l >> 4;
        const int n = fi >> 4, Ks = fi & 15;
        const int ch = n * 16 + lr2, k = Ks * 32 + lg2 * 8 + e;
        w2tF[idx] = f2bf(ffw2[(size_t)k * D + ch]);
    }
    if (idx < 16 * D) {
        const int n = idx >> 7, k = idx & 127;
        w1p[idx] = (n < NH) ? f2bf(w1[(size_t)k * NH + n]) : (unsigned short)0;
        w2p[idx] = f2bf(w2[(size_t)k * HD + n]);
    }
    if (blockIdx.x < 2) {
        const int n = blockIdx.x * 256 + threadIdx.x;   // 0..511
        float c1 = 0.f, c2 = 0.f;
        for (int k = 0; k < D; ++k) {
            const float w = ffw1[(size_t)k * FF + n];
            c1 += g3[k] * w;
            c2 += b3[k] * w;
        }
        c1c2[n] = make_float2(c1, c2 + ffb1[n]);
    }
}

// ---------------------------------------------------------------------------
// Kernel 1 (merged), 512 threads (R27-verified): blocks [0,1176) = pair
// symmetrize+LN1+logits over 8x8 (i,j)-tiles; 8 threads/pair x 16 channels.
// Blocks [1176,+1536) = values LN2(m)@w2 -> VtT (8 thr/row x 16ch).
// MFMA phases gated to waves 0-3.
// ---------------------------------------------------------------------------
__global__ void k_plv(const float* __restrict__ x,
                      const float* __restrict__ g1,
                      const float* __restrict__ bt1,
                      const unsigned short* __restrict__ w1p,
                      const float* __restrict__ b1,
                      float* __restrict__ logits,
                      const float* __restrict__ m_,
                      const float* __restrict__ g2,
                      const float* __restrict__ bt2,
                      const unsigned short* __restrict__ w2p,
                      const float* __restrict__ b2,
                      unsigned short* __restrict__ VtT) {
    __shared__ __align__(16) char smem[32768];   // xstage 32KB / nrm 17.4KB union
    __shared__ int ij[64];
    float* xstage = (float*)smem;                // [64 slots][128 floats]
    unsigned short (*nrm)[136] = (unsigned short(*)[136])smem;
    const int tid = threadIdx.x;

    if (blockIdx.x < NPAIRT) {
        // ---------------- pair_logits body, tiled ----------------
        const int q = blockIdx.x;
        int t = (int)((97.0f - sqrtf((float)(9409 - 8 * q))) * 0.5f);
        while ((t + 1) * (97 - (t + 1)) / 2 <= q) ++t;
        while (t * (97 - t) / 2 > q) --t;
        const int ti = t;
        const int tj = t + (q - t * (97 - t) / 2);

        const int pr = tid >> 3, part = tid & 7;   // 64 pairs x 8 parts(16ch)
        const int il = pr >> 3, jl = pr & 7;
        const int i = ti * 8 + il, j = tj * 8 + jl;
        if (part == 0) ij[pr] = (i << 16) | j;

        const int po = part >> 1;                  // old 32-ch part 0..3
        const int qb = (part & 1) * 4;             // q8 base within old part

        // load A: own pair's x[i][j] 64B sub-chunk (coalesced)
        const float4* xa = (const float4*)(x + ((size_t)i * L + j) * D + part * 16);
        float4 a[4];
        #pragma unroll
        for (int qq = 0; qq < 4; ++qq) a[qq] = xa[qq];

        // load B: x[tj*8+il][ti*8+jl] (coalesced); stage into swizzled LDS
        {
            const int sw  = pr;
            const int swz = (sw ^ (sw >> 3)) & 7;
            const float4* xbsrc = (const float4*)(x +
                ((size_t)(tj * 8 + il) * L + (ti * 8 + jl)) * D + part * 16);
            float* rowp = xstage + sw * 128 + po * 32;
            #pragma unroll
            for (int qq = 0; qq < 4; ++qq) {
                const int q8 = qb + qq;
                *(float4*)(rowp + ((q8 ^ swz) << 2)) = xbsrc[qq];
            }
        }
        __syncthreads();

        // read own xb from slot sr = jl*8+il; symmetrize + LN stats
        float v[16];
        float s = 0.f, sq = 0.f;
        {
            const int sr  = jl * 8 + il;
            const int swz = (sr ^ (sr >> 3)) & 7;
            const float* rowp = xstage + sr * 128 + po * 32;
            #pragma unroll
            for (int qq = 0; qq < 4; ++qq) {
                const int q8 = qb + qq;
                const float4 b = *(const float4*)(rowp + ((q8 ^ swz) << 2));
                const float t0 = 0.5f * (a[qq].x + b.x), t1 = 0.5f * (a[qq].y + b.y);
                const float t2 = 0.5f * (a[qq].z + b.z), t3 = 0.5f * (a[qq].w + b.w);
                v[qq*4+0] = t0; v[qq*4+1] = t1; v[qq*4+2] = t2; v[qq*4+3] = t3;
                s  += t0 + t1 + t2 + t3;
                sq += t0*t0 + t1*t1 + t2*t2 + t3*t3;
            }
        }
        s  += __shfl_xor(s, 1);  s  += __shfl_xor(s, 2);  s  += __shfl_xor(s, 4);
        sq += __shfl_xor(sq, 1); sq += __shfl_xor(sq, 2); sq += __shfl_xor(sq, 4);
        const float mean = s * (1.0f / D);
        const float rstd = rsqrtf(sq * (1.0f / D) - mean * mean + 1e-5f);

        __syncthreads();   // all xstage reads done before nrm overwrites smem

        #pragma unroll
        for (int qq = 0; qq < 4; ++qq) {
            const int c = part * 16 + qq * 4;
            ushort4 pk;
            pk.x = f2bf((v[qq*4+0] - mean) * rstd * g1[c+0] + bt1[c+0]);
            pk.y = f2bf((v[qq*4+1] - mean) * rstd * g1[c+1] + bt1[c+1]);
            pk.z = f2bf((v[qq*4+2] - mean) * rstd * g1[c+2] + bt1[c+2]);
            pk.w = f2bf((v[qq*4+3] - mean) * rstd * g1[c+3] + bt1[c+3]);
            *(ushort4*)(&nrm[pr][c]) = pk;
        }
        __syncthreads();

        if ((tid >> 6) < 4) {
            const int wv = tid >> 6, lane = tid & 63;
            const int lr = lane & 15, lg = lane >> 4;
            f32x4 acc = {0.f, 0.f, 0.f, 0.f};
            #pragma unroll
            for (int ks = 0; ks < 4; ++ks) {
                bf16x8 av = *(const bf16x8*)(&nrm[wv * 16 + lr][ks * 32 + lg * 8]);
                bf16x8 bv = *(const bf16x8*)(w1p + (size_t)lr * D + ks * 32 + lg * 8);
                acc = MFMA16(av, bv, acc);
            }
            if (lr < NH) {
                #pragma unroll
                for (int r = 0; r < 4; ++r) {
                    const int pl = wv * 16 + lg * 4 + r;
                    const int pij = ij[pl];
                    const int pi = pij >> 16, pj = pij & 0xffff;
                    const float val = acc[r] + b1[lr];
                    logits[((size_t)pi * L + pj) * NH + lr] = val;
                    logits[((size_t)pj * L + pi) * NH + lr] = val;
                }
            }
        }
    } else {
        // ---------------- values body (64-j tile, 8 thr/row) ----------------
        const int vb = blockIdx.x - NPAIRT;      // 0..1535
        const int r  = vb / 6;
        const int j0 = (vb % 6) * 64;
        {
            const int row = tid >> 3, part = tid & 7;
            const float* src = m_ + ((size_t)r * L + j0 + row) * D + part * 16;
            float v[16];
            float s = 0.f, sq = 0.f;
            #pragma unroll
            for (int qq = 0; qq < 4; ++qq) {
                const float4 a = ((const float4*)src)[qq];
                v[qq*4+0] = a.x; v[qq*4+1] = a.y; v[qq*4+2] = a.z; v[qq*4+3] = a.w;
                s  += a.x + a.y + a.z + a.w;
                sq += a.x*a.x + a.y*a.y + a.z*a.z + a.w*a.w;
            }
            s  += __shfl_xor(s, 1);  s  += __shfl_xor(s, 2);  s  += __shfl_xor(s, 4);
            sq += __shfl_xor(sq, 1); sq += __shfl_xor(sq, 2); sq += __shfl_xor(sq, 4);
            const float mean = s * (1.0f / D);
            const float rstd = rsqrtf(sq * (1.0f / D) - mean * mean + 1e-5f);
            #pragma unroll
            for (int qq = 0; qq < 4; ++qq) {
                const int c = part * 16 + qq * 4;
                ushort4 pk;
                pk.x = f2bf((v[qq*4+0] - mean) * rstd * g2[c+0] + bt2[c+0]);
                pk.y = f2bf((v[qq*4+1] - mean) * rstd * g2[c+1] + bt2[c+1]);
                pk.z = f2bf((v[qq*4+2] - mean) * rstd * g2[c+2] + bt2[c+2]);
                pk.w = f2bf((v[qq*4+3] - mean) * rstd * g2[c+3] + bt2[c+3]);
                *(ushort4*)(&nrm[row][c]) = pk;
            }
        }
        __syncthreads();
        if ((tid >> 6) < 4) {
            const int wv = tid >> 6, lane = tid & 63;
            const int lr = lane & 15, lg = lane >> 4;
            f32x4 acc = {0.f, 0.f, 0.f, 0.f};
            #pragma unroll
            for (int ks = 0; ks < 4; ++ks) {
                bf16x8 b = *(const bf16x8*)(w2p + (size_t)lr * D + ks * 32 + lg * 8);
                bf16x8 a = *(const bf16x8*)(&nrm[wv * 16 + lr][ks * 32 + lg * 8]);
                acc = MFMA16(a, b, acc);
            }
            const float bb = b2[lr];
            ushort4 pk;
            pk.x = f2bf(acc[0] + bb);
            pk.y = f2bf(acc[1] + bb);
            pk.z = f2bf(acc[2] + bb);
            pk.w = f2bf(acc[3] + bb);
            *(ushort4*)(VtT + (size_t)(r * HD + lr) * L + j0 + wv * 16 + lg * 4) = pk;
        }
    }
}

// ---------------------------------------------------------------------------
// Kernel 2: softmax over j for each (i,h); logits f32 -> attnT bf16 [h][i][j]
// ---------------------------------------------------------------------------
__global__ void k_softmax(const float* __restrict__ logits,
                          unsigned short* __restrict__ attnT) {
    const int wave = blockIdx.x * 4 + (threadIdx.x >> 6);
    const int lane = threadIdx.x & 63;
    const int i = wave >> 3, h = wave & 7;

    float v[6];
    float mx = -1e30f;
    #pragma unroll
    for (int t = 0; t < 6; ++t) {
        const int j = lane + t * 64;
        v[t] = logits[((size_t)i * L + j) * NH + h];
        mx = fmaxf(mx, v[t]);
    }
    #pragma unroll
    for (int msk = 32; msk; msk >>= 1) mx = fmaxf(mx, __shfl_xor(mx, msk));

    float s = 0.0f;
    #pragma unroll
    for (int t = 0; t < 6; ++t) { v[t] = __expf(v[t] - mx); s += v[t]; }
    #pragma unroll
    for (int msk = 32; msk; msk >>= 1) s += __shfl_xor(s, msk);
    const float inv = 1.0f / s;

    #pragma unroll
    for (int t = 0; t < 6; ++t) {
        const int j = lane + t * 64;
        attnT[((size_t)h * L + i) * L + j] = f2bf(v[t] * inv);
    }
}

// ---------------------------------------------------------------------------
// Kernel 4: einsum via MFMA (R13-verified body). Epilogue writes bf16 outb.
// ---------------------------------------------------------------------------
__global__ void k_attn_out(const unsigned short* __restrict__ attnT,
                           const unsigned short* __restrict__ VtT,
                           const float* __restrict__ min_,
                           unsigned short* __restrict__ outb) {
    const int h  = blockIdx.z;
    const int i0 = blockIdx.x * 128;
    const int n0 = blockIdx.y * 128;
    const int tid = threadIdx.x, wv = tid >> 6, lane = tid & 63;
    const int lr = lane & 15, lg = lane >> 4;
    const int wio = (wv >> 1) * 64, wno = (wv & 1) * 64;
    const unsigned short* Abase = attnT + (size_t)h * L * L;

    f32x4 acc[4][4];
    #pragma unroll
    for (int a = 0; a < 4; ++a)
        #pragma unroll
        for (int b = 0; b < 4; ++b) acc[a][b] = (f32x4){0.f, 0.f, 0.f, 0.f};

    bf16x8 af[4], bf[4], afn[4], bfn[4];
    #pragma unroll
    for (int mt = 0; mt < 4; ++mt)
        af[mt] = *(const bf16x8*)(Abase + (size_t)(i0 + wio + mt * 16 + lr) * L + lg * 8);
    #pragma unroll
    for (int nt = 0; nt < 4; ++nt)
        bf[nt] = *(const bf16x8*)(VtT + (size_t)(n0 + wno + nt * 16 + lr) * L + lg * 8);

    for (int ks = 0; ks < 12; ++ks) {
        if (ks < 11) {
            const int ko = (ks + 1) * 32 + lg * 8;
            #pragma unroll
            for (int mt = 0; mt < 4; ++mt)
                afn[mt] = *(const bf16x8*)(Abase + (size_t)(i0 + wio + mt * 16 + lr) * L + ko);
            #pragma unroll
            for (int nt = 0; nt < 4; ++nt)
                bfn[nt] = *(const bf16x8*)(VtT + (size_t)(n0 + wno + nt * 16 + lr) * L + ko);
        }
        #pragma unroll
        for (int mt = 0; mt < 4; ++mt)
            #pragma unroll
            for (int nt = 0; nt < 4; ++nt)
                acc[mt][nt] = MFMA16(af[mt], bf[nt], acc[mt][nt]);
        #pragma unroll
        for (int q = 0; q < 4; ++q) { af[q] = afn[q]; bf[q] = bfn[q]; }
    }

    #pragma unroll
    for (int mt = 0; mt < 4; ++mt) {
        #pragma unroll
        for (int nt = 0; nt < 4; ++nt) {
            const int nbase = n0 + wno + nt * 16;
            const int rrow  = nbase >> 4;
            #pragma unroll
            for (int r = 0; r < 4; ++r) {
                const int i = i0 + wio + mt * 16 + lg * 4 + r;
                const size_t gidx = ((size_t)rrow * L + i) * D + h * HD + lr;
                outb[gidx] = f2bf(min_[gidx] + acc[mt][nt][r]);
            }
        }
    }
}

// ---------------------------------------------------------------------------
// Kernel 5: FUSED FFN v8 — R17 structure with SINGLE-buffer hid (LDS 32.5KB
// -> 4 blocks/CU = 32 waves/CU) at the cost of one extra barrier per kc.
// Per-block work and register liveness identical to the verified v7.
// ---------------------------------------------------------------------------
__global__ __launch_bounds__(512, 4) void k_ffn(
                      const unsigned short* __restrict__ outb,
                      const unsigned short* __restrict__ w1gF,
                      const float2* __restrict__ c1c2,
                      const unsigned short* __restrict__ w2tF,
                      const float* __restrict__ ffb2,
                      float* __restrict__ out) {
    __shared__ unsigned short At[64 * 128];     // 16 KB, row-XOR swizzled
    __shared__ unsigned short hid[64 * 128];    // 16 KB single buffer, swizzled
    __shared__ float2 stats[64];                // (rstd, mu*rstd)
    const int tid = threadIdx.x;
    const size_t row0 = (size_t)blockIdx.x * 64;

    const int wv = tid >> 6, lane = tid & 63;
    const int lr = lane & 15, lg = lane >> 4;
    const int wm = wv >> 2, wn = wv & 3;          // 2(M:32rows) x 4(N:32cols)

    // ---- preload W1 fragments for kc=0 (overlaps A-staging) ----
    bf16x8 w1f[8], w2f[8];
    #pragma unroll
    for (int ks = 0; ks < 4; ++ks)
        #pragma unroll
        for (int nt = 0; nt < 2; ++nt) {
            const int fi = (0 * 8 + wn * 2 + nt) * 4 + ks;
            w1f[ks * 2 + nt] = *(const bf16x8*)((const char*)w1gF + fi * 1024 + lane * 16);
        }

    // ---- Stage A (bf16 copy) + inline LN3 stats: 8 thr/row x 16 ch ----
    {
        const int rr = tid >> 3, part = tid & 7;
        const unsigned short* src = outb + (row0 + rr) * D + part * 16;
        const uint4 v0 = *(const uint4*)(src);       // 8 bf16
        const uint4 v1 = *(const uint4*)(src + 8);   // 8 bf16
        float s = 0.f, sq = 0.f;
        const unsigned w[8] = {v0.x, v0.y, v0.z, v0.w, v1.x, v1.y, v1.z, v1.w};
        #pragma unroll
        for (int e = 0; e < 8; ++e) {
            const float lo = __builtin_bit_cast(float, w[e] << 16);
            const float hi = __builtin_bit_cast(float, w[e] & 0xffff0000u);
            s  += lo + hi;
            sq += lo * lo + hi * hi;
        }
        s  += __shfl_xor(s, 1);  s  += __shfl_xor(s, 2);  s  += __shfl_xor(s, 4);
        sq += __shfl_xor(sq, 1); sq += __shfl_xor(sq, 2); sq += __shfl_xor(sq, 4);
        if (part == 0) {
            const float mean = s * (1.0f / D);
            const float rstd = rsqrtf(sq * (1.0f / D) - mean * mean + 1e-5f);
            stats[rr] = make_float2(rstd, mean * rstd);
        }
        const int xr = (rr & 7) << 4;
        char* rowp = (char*)(At + rr * 128);
        const int cb = part * 32;                 // byte offset of 16 bf16
        *(uint4*)(rowp + ((cb     ) ^ xr)) = v0;
        *(uint4*)(rowp + ((cb + 16) ^ xr)) = v1;
    }

    // ---- preload W2 fragments for kc=0 ----
    #pragma unroll
    for (int ks = 0; ks < 4; ++ks)
        #pragma unroll
        for (int nt = 0; nt < 2; ++nt) {
            const int fi = (wn * 2 + nt) * 16 + 0 * 4 + ks;
            w2f[ks * 2 + nt] = *(const bf16x8*)((const char*)w2tF + fi * 1024 + lane * 16);
        }

    __syncthreads();

    f32x4 acc2[2][2];
    #pragma unroll
    for (int m = 0; m < 2; ++m)
        #pragma unroll
        for (int n = 0; n < 2; ++n) acc2[m][n] = (f32x4){0.f, 0.f, 0.f, 0.f};

    #pragma unroll
    for (int kc = 0; kc < 4; ++kc) {
        // ---- GEMM1-chunk -> hid (single buffer) ----
        {
            f32x4 acc1[2][2];
            #pragma unroll
            for (int m = 0; m < 2; ++m)
                #pragma unroll
                for (int n = 0; n < 2; ++n) acc1[m][n] = (f32x4){0.f, 0.f, 0.f, 0.f};

            #pragma unroll
            for (int ks = 0; ks < 4; ++ks) {
                bf16x8 af[2];
                #pragma unroll
                for (int mt = 0; mt < 2; ++mt) {
                    const int row = wm * 32 + mt * 16 + lr;
                    af[mt] = *(const bf16x8*)((char*)(At + row * 128) +
                              ((ks * 64 + lg * 16) ^ ((row & 7) << 4)));
                }
                #pragma unroll
                for (int mt = 0; mt < 2; ++mt)
                    #pragma unroll
                    for (int nt = 0; nt < 2; ++nt)
                        acc1[mt][nt] = MFMA16(af[mt], w1f[ks * 2 + nt], acc1[mt][nt]);
            }

            #pragma unroll
            for (int nt = 0; nt < 2; ++nt) {
                const int chl = wn * 32 + nt * 16 + lr;        // 0..127
                const float2 cc = c1c2[kc * 128 + chl];
                #pragma unroll
                for (int mt = 0; mt < 2; ++mt) {
                    #pragma unroll
                    for (int r = 0; r < 4; ++r) {
                        const int row = wm * 32 + mt * 16 + lg * 4 + r;
                        const float2 st = stats[row];
                        const float pre = st.x * acc1[mt][nt][r] - st.y * cc.x + cc.y;
                        *(unsigned short*)((char*)(hid + row * 128) +
                            ((chl * 2) ^ ((row & 7) << 4))) = f2bf(fmaxf(pre, 0.f));
                    }
                }
            }
        }
        __syncthreads();   // hid writes visible

        // refill W1 for kc+1 AFTER the barrier (overlaps GEMM2)
        if (kc < 3) {
            #pragma unroll
            for (int ks = 0; ks < 4; ++ks)
                #pragma unroll
                for (int nt = 0; nt < 2; ++nt) {
                    const int fi = ((kc + 1) * 8 + wn * 2 + nt) * 4 + ks;
                    w1f[ks * 2 + nt] = *(const bf16x8*)((const char*)w1gF + fi * 1024 + lane * 16);
                }
        }

        // ---- GEMM2-chunk ----
        {
            #pragma unroll
            for (int ks = 0; ks < 4; ++ks) {
                bf16x8 hf[2];
                #pragma unroll
                for (int mt = 0; mt < 2; ++mt) {
                    const int row = wm * 32 + mt * 16 + lr;
                    hf[mt] = *(const bf16x8*)((char*)(hid + row * 128) +
                              ((ks * 64 + lg * 16) ^ ((row & 7) << 4)));
                }
                #pragma unroll
                for (int mt = 0; mt < 2; ++mt)
                    #pragma unroll
                    for (int nt = 0; nt < 2; ++nt)
                        acc2[mt][nt] = MFMA16(hf[mt], w2f[ks * 2 + nt], acc2[mt][nt]);
            }
        }

        // refill W2 for kc+1; barrier so next GEMM1 may overwrite hid
        if (kc < 3) {
            #pragma unroll
            for (int ks = 0; ks < 4; ++ks)
                #pragma unroll
                for (int nt = 0; nt < 2; ++nt) {
                    const int fi = (wn * 2 + nt) * 16 + (kc + 1) * 4 + ks;
                    w2f[ks * 2 + nt] = *(const bf16x8*)((const char*)w2tF + fi * 1024 + lane * 16);
                }
            __syncthreads();   // hid reads done before next GEMM1 writes
        }
    }

    // ---- epilogue: out = bf2f(At) + acc2 + ffb2 (pure store, no RMW) ----
    #pragma unroll
    for (int nt = 0; nt < 2; ++nt) {
        const int ch = wn * 32 + nt * 16 + lr;
        const float bb = ffb2[ch];
        #pragma unroll
        for (int mt = 0; mt < 2; ++mt) {
            #pragma unroll
            for (int r = 0; r < 4; ++r) {
                const int row = wm * 32 + mt * 16 + lg * 4 + r;
                const float resid = bf2f(*(const unsigned short*)((char*)(At + row * 128) +
                                     ((ch * 2) ^ ((row & 7) << 4))));
                out[(row0 + row) * (size_t)D + ch] = resid + acc2[mt][nt][r] + bb;
            }
        }
    }
}

// ---------------------------------------------------------------------------
extern "C" void kernel_launch(void* const* d_in, const int* in_sizes, int n_in,
                              void* d_out, int out_size, void* d_ws, size_t ws_size,
                              hipStream_t stream) {
    const float* x     = (const float*)d_in[0];
    const float* m     = (const float*)d_in[1];
    const float* ln1_g = (const float*)d_in[2];
    const float* ln1_b = (const float*)d_in[3];
    const float* ln2_g = (const float*)d_in[4];
    const float* ln2_b = (const float*)d_in[5];
    const float* ln3_g = (const float*)d_in[6];
    const float* ln3_b = (const float*)d_in[7];
    const float* w1    = (const float*)d_in[8];
    const float* b1    = (const float*)d_in[9];
    const float* w2    = (const float*)d_in[10];
    const float* b2    = (const float*)d_in[11];
    const float* ffw1  = (const float*)d_in[12];
    const float* ffb1  = (const float*)d_in[13];
    const float* ffw2  = (const float*)d_in[14];
    const float* ffb2  = (const float*)d_in[15];

    float* out = (float*)d_out;

    char* wsp = (char*)d_ws;
    float*          logits = (float*)wsp;              wsp += (size_t)L*L*NH*4;   // 4.72 MB
    unsigned short* attnT  = (unsigned short*)wsp;     wsp += (size_t)NH*L*L*2;   // 2.36 MB
    unsigned short* VtT    = (unsigned short*)wsp;     wsp += (size_t)R*HD*L*2;   // 3.15 MB
    unsigned short* w1gF   = (unsigned short*)wsp;     wsp += (size_t)FF*D*2;     // 128 KB
    unsigned short* w2tF   = (unsigned short*)wsp;     wsp += (size_t)D*FF*2;     // 128 KB
    unsigned short* w1p    = (unsigned short*)wsp;     wsp += (size_t)16*D*2;     // 4 KB
    unsigned short* w2p    = (unsigned short*)wsp;     wsp += (size_t)16*D*2;     // 4 KB
    float2*         c1c2   = (float2*)wsp;             wsp += (size_t)FF*8;       // 4 KB
    unsigned short* outb   = (unsigned short*)wsp;     wsp += (size_t)R*L*D*2;    // 25.2 MB

    k_prep<<<(FF * D) / 256, 256, 0, stream>>>(w1, w2, ffw1, ffw2,
                                               ln3_g, ln3_b, ffb1,
                                               w1p, w2p, w1gF, w2tF, c1c2);

    // merged: 1176 tile pair-logit blocks + 1536 values blocks (512 threads)
    k_plv<<<NPAIRT + R * 6, 512, 0, stream>>>(x, ln1_g, ln1_b, w1p, b1, logits,
                                              m, ln2_g, ln2_b, w2p, b2, VtT);

    k_softmax<<<(L * NH) / 4, 256, 0, stream>>>(logits, attnT);

    dim3 g4(L / 128, (R * HD) / 128, NH);
    k_attn_out<<<g4, 256, 0, stream>>>(attnT, VtT, m, outb);

    k_ffn<<<(R * L) / 64, 512, 0, stream>>>(outb, w1gF, c1c2, w2tF, ffb2, out);
}

// Round 29
// 128.388 us; speedup vs baseline: 1.0986x; 1.0986x over previous
//
#include <hip/hip_runtime.h>

typedef __attribute__((ext_vector_type(8))) short bf16x8;
typedef __attribute__((ext_vector_type(4))) float f32x4;

constexpr int L  = 384;
constexpr int R  = 256;
constexpr int D  = 128;
constexpr int NH = 8;
constexpr int HD = 16;
constexpr int FF = 512;

constexpr int NTILE  = 48;                 // L/8
constexpr int NPAIRT = NTILE * (NTILE + 1) / 2;   // 1176 tile blocks

#define MFMA16(a, b, c) __builtin_amdgcn_mfma_f32_16x16x32_bf16((a), (b), (c), 0, 0, 0)

__device__ inline unsigned short f2bf(float f) {
    unsigned u = __builtin_bit_cast(unsigned, f);
    u += 0x7fffu + ((u >> 16) & 1u);          // round-to-nearest-even
    return (unsigned short)(u >> 16);
}
__device__ inline float bf2f(unsigned short h) {
    unsigned u = ((unsigned)h) << 16;
    return __builtin_bit_cast(float, u);
}

// ---------------------------------------------------------------------------
// Prep: attn weights (w1p/w2p), LN3-fold constants, FRAGMENTIZED FFN weights
// ---------------------------------------------------------------------------
__global__ void k_prep(const float* __restrict__ w1,
                       const float* __restrict__ w2,
                       const float* __restrict__ ffw1,
                       const float* __restrict__ ffw2,
                       const float* __restrict__ g3,
                       const float* __restrict__ b3,
                       const float* __restrict__ ffb1,
                       unsigned short* __restrict__ w1p,
                       unsigned short* __restrict__ w2p,
                       unsigned short* __restrict__ w1gF,
                       unsigned short* __restrict__ w2tF,
                       float2* __restrict__ c1c2) {
    const int idx = blockIdx.x * 256 + threadIdx.x;   // 65536 threads
    {
        const int fi = idx >> 9, rem = idx & 511, l = rem >> 3, e = rem & 7;
        const int lr2 = l & 15, lg2 = l >> 4;
        const int n = fi >> 2, ks = fi & 3;
        const int ch = n * 16 + lr2, k = ks * 32 + lg2 * 8 + e;
        w1gF[idx] = f2bf(g3[k] * ffw1[(size_t)k * FF + ch]);
    }
    {
        const int fi = idx >> 9, rem = idx & 511, l = rem >> 3, e = rem & 7;
        const int lr2 = l & 15, lg2 = l >> 4;
        const int n = fi >> 4, Ks = fi & 15;
        const int ch = n * 16 + lr2, k = Ks * 32 + lg2 * 8 + e;
        w2tF[idx] = f2bf(ffw2[(size_t)k * D + ch]);
    }
    if (idx < 16 * D) {
        const int n = idx >> 7, k = idx & 127;
        w1p[idx] = (n < NH) ? f2bf(w1[(size_t)k * NH + n]) : (unsigned short)0;
        w2p[idx] = f2bf(w2[(size_t)k * HD + n]);
    }
    if (blockIdx.x < 2) {
        const int n = blockIdx.x * 256 + threadIdx.x;   // 0..511
        float c1 = 0.f, c2 = 0.f;
        for (int k = 0; k < D; ++k) {
            const float w = ffw1[(size_t)k * FF + n];
            c1 += g3[k] * w;
            c2 += b3[k] * w;
        }
        c1c2[n] = make_float2(c1, c2 + ffb1[n]);
    }
}

// ---------------------------------------------------------------------------
// Kernel 1 (merged), 512 threads (R27-verified): blocks [0,1176) = pair
// symmetrize+LN1+logits over 8x8 (i,j)-tiles; 8 threads/pair x 16 channels.
// Blocks [1176,+1536) = values LN2(m)@w2 -> VtT (8 thr/row x 16ch).
// MFMA phases gated to waves 0-3.
// ---------------------------------------------------------------------------
__global__ void k_plv(const float* __restrict__ x,
                      const float* __restrict__ g1,
                      const float* __restrict__ bt1,
                      const unsigned short* __restrict__ w1p,
                      const float* __restrict__ b1,
                      float* __restrict__ logits,
                      const float* __restrict__ m_,
                      const float* __restrict__ g2,
                      const float* __restrict__ bt2,
                      const unsigned short* __restrict__ w2p,
                      const float* __restrict__ b2,
                      unsigned short* __restrict__ VtT) {
    __shared__ __align__(16) char smem[32768];   // xstage 32KB / nrm 17.4KB union
    __shared__ int ij[64];
    float* xstage = (float*)smem;                // [64 slots][128 floats]
    unsigned short (*nrm)[136] = (unsigned short(*)[136])smem;
    const int tid = threadIdx.x;

    if (blockIdx.x < NPAIRT) {
        // ---------------- pair_logits body, tiled ----------------
        const int q = blockIdx.x;
        int t = (int)((97.0f - sqrtf((float)(9409 - 8 * q))) * 0.5f);
        while ((t + 1) * (97 - (t + 1)) / 2 <= q) ++t;
        while (t * (97 - t) / 2 > q) --t;
        const int ti = t;
        const int tj = t + (q - t * (97 - t) / 2);

        const int pr = tid >> 3, part = tid & 7;   // 64 pairs x 8 parts(16ch)
        const int il = pr >> 3, jl = pr & 7;
        const int i = ti * 8 + il, j = tj * 8 + jl;
        if (part == 0) ij[pr] = (i << 16) | j;

        const int po = part >> 1;                  // old 32-ch part 0..3
        const int qb = (part & 1) * 4;             // q8 base within old part

        // load A: own pair's x[i][j] 64B sub-chunk (coalesced)
        const float4* xa = (const float4*)(x + ((size_t)i * L + j) * D + part * 16);
        float4 a[4];
        #pragma unroll
        for (int qq = 0; qq < 4; ++qq) a[qq] = xa[qq];

        // load B: x[tj*8+il][ti*8+jl] (coalesced); stage into swizzled LDS
        {
            const int sw  = pr;
            const int swz = (sw ^ (sw >> 3)) & 7;
            const float4* xbsrc = (const float4*)(x +
                ((size_t)(tj * 8 + il) * L + (ti * 8 + jl)) * D + part * 16);
            float* rowp = xstage + sw * 128 + po * 32;
            #pragma unroll
            for (int qq = 0; qq < 4; ++qq) {
                const int q8 = qb + qq;
                *(float4*)(rowp + ((q8 ^ swz) << 2)) = xbsrc[qq];
            }
        }
        __syncthreads();

        // read own xb from slot sr = jl*8+il; symmetrize + LN stats
        float v[16];
        float s = 0.f, sq = 0.f;
        {
            const int sr  = jl * 8 + il;
            const int swz = (sr ^ (sr >> 3)) & 7;
            const float* rowp = xstage + sr * 128 + po * 32;
            #pragma unroll
            for (int qq = 0; qq < 4; ++qq) {
                const int q8 = qb + qq;
                const float4 b = *(const float4*)(rowp + ((q8 ^ swz) << 2));
                const float t0 = 0.5f * (a[qq].x + b.x), t1 = 0.5f * (a[qq].y + b.y);
                const float t2 = 0.5f * (a[qq].z + b.z), t3 = 0.5f * (a[qq].w + b.w);
                v[qq*4+0] = t0; v[qq*4+1] = t1; v[qq*4+2] = t2; v[qq*4+3] = t3;
                s  += t0 + t1 + t2 + t3;
                sq += t0*t0 + t1*t1 + t2*t2 + t3*t3;
            }
        }
        s  += __shfl_xor(s, 1);  s  += __shfl_xor(s, 2);  s  += __shfl_xor(s, 4);
        sq += __shfl_xor(sq, 1); sq += __shfl_xor(sq, 2); sq += __shfl_xor(sq, 4);
        const float mean = s * (1.0f / D);
        const float rstd = rsqrtf(sq * (1.0f / D) - mean * mean + 1e-5f);

        __syncthreads();   // all xstage reads done before nrm overwrites smem

        #pragma unroll
        for (int qq = 0; qq < 4; ++qq) {
            const int c = part * 16 + qq * 4;
            ushort4 pk;
            pk.x = f2bf((v[qq*4+0] - mean) * rstd * g1[c+0] + bt1[c+0]);
            pk.y = f2bf((v[qq*4+1] - mean) * rstd * g1[c+1] + bt1[c+1]);
            pk.z = f2bf((v[qq*4+2] - mean) * rstd * g1[c+2] + bt1[c+2]);
            pk.w = f2bf((v[qq*4+3] - mean) * rstd * g1[c+3] + bt1[c+3]);
            *(ushort4*)(&nrm[pr][c]) = pk;
        }
        __syncthreads();

        if ((tid >> 6) < 4) {
            const int wv = tid >> 6, lane = tid & 63;
            const int lr = lane & 15, lg = lane >> 4;
            f32x4 acc = {0.f, 0.f, 0.f, 0.f};
            #pragma unroll
            for (int ks = 0; ks < 4; ++ks) {
                bf16x8 av = *(const bf16x8*)(&nrm[wv * 16 + lr][ks * 32 + lg * 8]);
                bf16x8 bv = *(const bf16x8*)(w1p + (size_t)lr * D + ks * 32 + lg * 8);
                acc = MFMA16(av, bv, acc);
            }
            if (lr < NH) {
                #pragma unroll
                for (int r = 0; r < 4; ++r) {
                    const int pl = wv * 16 + lg * 4 + r;
                    const int pij = ij[pl];
                    const int pi = pij >> 16, pj = pij & 0xffff;
                    const float val = acc[r] + b1[lr];
                    logits[((size_t)pi * L + pj) * NH + lr] = val;
                    logits[((size_t)pj * L + pi) * NH + lr] = val;
                }
            }
        }
    } else {
        // ---------------- values body (64-j tile, 8 thr/row) ----------------
        const int vb = blockIdx.x - NPAIRT;      // 0..1535
        const int r  = vb / 6;
        const int j0 = (vb % 6) * 64;
        {
            const int row = tid >> 3, part = tid & 7;
            const float* src = m_ + ((size_t)r * L + j0 + row) * D + part * 16;
            float v[16];
            float s = 0.f, sq = 0.f;
            #pragma unroll
            for (int qq = 0; qq < 4; ++qq) {
                const float4 a = ((const float4*)src)[qq];
                v[qq*4+0] = a.x; v[qq*4+1] = a.y; v[qq*4+2] = a.z; v[qq*4+3] = a.w;
                s  += a.x + a.y + a.z + a.w;
                sq += a.x*a.x + a.y*a.y + a.z*a.z + a.w*a.w;
            }
            s  += __shfl_xor(s, 1);  s  += __shfl_xor(s, 2);  s  += __shfl_xor(s, 4);
            sq += __shfl_xor(sq, 1); sq += __shfl_xor(sq, 2); sq += __shfl_xor(sq, 4);
            const float mean = s * (1.0f / D);
            const float rstd = rsqrtf(sq * (1.0f / D) - mean * mean + 1e-5f);
            #pragma unroll
            for (int qq = 0; qq < 4; ++qq) {
                const int c = part * 16 + qq * 4;
                ushort4 pk;
                pk.x = f2bf((v[qq*4+0] - mean) * rstd * g2[c+0] + bt2[c+0]);
                pk.y = f2bf((v[qq*4+1] - mean) * rstd * g2[c+1] + bt2[c+1]);
                pk.z = f2bf((v[qq*4+2] - mean) * rstd * g2[c+2] + bt2[c+2]);
                pk.w = f2bf((v[qq*4+3] - mean) * rstd * g2[c+3] + bt2[c+3]);
                *(ushort4*)(&nrm[row][c]) = pk;
            }
        }
        __syncthreads();
        if ((tid >> 6) < 4) {
            const int wv = tid >> 6, lane = tid & 63;
            const int lr = lane & 15, lg = lane >> 4;
            f32x4 acc = {0.f, 0.f, 0.f, 0.f};
            #pragma unroll
            for (int ks = 0; ks < 4; ++ks) {
                bf16x8 b = *(const bf16x8*)(w2p + (size_t)lr * D + ks * 32 + lg * 8);
                bf16x8 a = *(const bf16x8*)(&nrm[wv * 16 + lr][ks * 32 + lg * 8]);
                acc = MFMA16(a, b, acc);
            }
            const float bb = b2[lr];
            ushort4 pk;
            pk.x = f2bf(acc[0] + bb);
            pk.y = f2bf(acc[1] + bb);
            pk.z = f2bf(acc[2] + bb);
            pk.w = f2bf(acc[3] + bb);
            *(ushort4*)(VtT + (size_t)(r * HD + lr) * L + j0 + wv * 16 + lg * 4) = pk;
        }
    }
}

// ---------------------------------------------------------------------------
// Kernel 2: softmax over j for each (i,h); logits f32 -> attnT bf16 [h][i][j]
// ---------------------------------------------------------------------------
__global__ void k_softmax(const float* __restrict__ logits,
                          unsigned short* __restrict__ attnT) {
    const int wave = blockIdx.x * 4 + (threadIdx.x >> 6);
    const int lane = threadIdx.x & 63;
    const int i = wave >> 3, h = wave & 7;

    float v[6];
    float mx = -1e30f;
    #pragma unroll
    for (int t = 0; t < 6; ++t) {
        const int j = lane + t * 64;
        v[t] = logits[((size_t)i * L + j) * NH + h];
        mx = fmaxf(mx, v[t]);
    }
    #pragma unroll
    for (int msk = 32; msk; msk >>= 1) mx = fmaxf(mx, __shfl_xor(mx, msk));

    float s = 0.0f;
    #pragma unroll
    for (int t = 0; t < 6; ++t) { v[t] = __expf(v[t] - mx); s += v[t]; }
    #pragma unroll
    for (int msk = 32; msk; msk >>= 1) s += __shfl_xor(s, msk);
    const float inv = 1.0f / s;

    #pragma unroll
    for (int t = 0; t < 6; ++t) {
        const int j = lane + t * 64;
        attnT[((size_t)h * L + i) * L + j] = f2bf(v[t] * inv);
    }
}

// ---------------------------------------------------------------------------
// Kernel 4: einsum via MFMA (R13-verified body). Epilogue writes bf16 outb.
// ---------------------------------------------------------------------------
__global__ void k_attn_out(const unsigned short* __restrict__ attnT,
                           const unsigned short* __restrict__ VtT,
                           const float* __restrict__ min_,
                           unsigned short* __restrict__ outb) {
    const int h  = blockIdx.z;
    const int i0 = blockIdx.x * 128;
    const int n0 = blockIdx.y * 128;
    const int tid = threadIdx.x, wv = tid >> 6, lane = tid & 63;
    const int lr = lane & 15, lg = lane >> 4;
    const int wio = (wv >> 1) * 64, wno = (wv & 1) * 64;
    const unsigned short* Abase = attnT + (size_t)h * L * L;

    f32x4 acc[4][4];
    #pragma unroll
    for (int a = 0; a < 4; ++a)
        #pragma unroll
        for (int b = 0; b < 4; ++b) acc[a][b] = (f32x4){0.f, 0.f, 0.f, 0.f};

    bf16x8 af[4], bf[4], afn[4], bfn[4];
    #pragma unroll
    for (int mt = 0; mt < 4; ++mt)
        af[mt] = *(const bf16x8*)(Abase + (size_t)(i0 + wio + mt * 16 + lr) * L + lg * 8);
    #pragma unroll
    for (int nt = 0; nt < 4; ++nt)
        bf[nt] = *(const bf16x8*)(VtT + (size_t)(n0 + wno + nt * 16 + lr) * L + lg * 8);

    for (int ks = 0; ks < 12; ++ks) {
        if (ks < 11) {
            const int ko = (ks + 1) * 32 + lg * 8;
            #pragma unroll
            for (int mt = 0; mt < 4; ++mt)
                afn[mt] = *(const bf16x8*)(Abase + (size_t)(i0 + wio + mt * 16 + lr) * L + ko);
            #pragma unroll
            for (int nt = 0; nt < 4; ++nt)
                bfn[nt] = *(const bf16x8*)(VtT + (size_t)(n0 + wno + nt * 16 + lr) * L + ko);
        }
        #pragma unroll
        for (int mt = 0; mt < 4; ++mt)
            #pragma unroll
            for (int nt = 0; nt < 4; ++nt)
                acc[mt][nt] = MFMA16(af[mt], bf[nt], acc[mt][nt]);
        #pragma unroll
        for (int q = 0; q < 4; ++q) { af[q] = afn[q]; bf[q] = bfn[q]; }
    }

    #pragma unroll
    for (int mt = 0; mt < 4; ++mt) {
        #pragma unroll
        for (int nt = 0; nt < 4; ++nt) {
            const int nbase = n0 + wno + nt * 16;
            const int rrow  = nbase >> 4;
            #pragma unroll
            for (int r = 0; r < 4; ++r) {
                const int i = i0 + wio + mt * 16 + lg * 4 + r;
                const size_t gidx = ((size_t)rrow * L + i) * D + h * HD + lr;
                outb[gidx] = f2bf(min_[gidx] + acc[mt][nt][r]);
            }
        }
    }
}

// ---------------------------------------------------------------------------
// Kernel 5: FUSED FFN v7 (R17-verified: 64 rows, launch_bounds(512,4),
// bf16 outb staging, double-buffered hid, pure-store epilogue).
// ---------------------------------------------------------------------------
__global__ __launch_bounds__(512, 4) void k_ffn(
                      const unsigned short* __restrict__ outb,
                      const unsigned short* __restrict__ w1gF,
                      const float2* __restrict__ c1c2,
                      const unsigned short* __restrict__ w2tF,
                      const float* __restrict__ ffb2,
                      float* __restrict__ out) {
    __shared__ unsigned short At[64 * 128];     // 16 KB, row-XOR swizzled
    __shared__ unsigned short hid[2][64 * 128]; // 2 x 16 KB, swizzled
    __shared__ float2 stats[64];                // (rstd, mu*rstd)
    const int tid = threadIdx.x;
    const size_t row0 = (size_t)blockIdx.x * 64;

    const int wv = tid >> 6, lane = tid & 63;
    const int lr = lane & 15, lg = lane >> 4;
    const int wm = wv >> 2, wn = wv & 3;          // 2(M:32rows) x 4(N:32cols)

    // ---- preload W1 fragments for kc=0 (overlaps A-staging) ----
    bf16x8 w1f[8], w2f[8];
    #pragma unroll
    for (int ks = 0; ks < 4; ++ks)
        #pragma unroll
        for (int nt = 0; nt < 2; ++nt) {
            const int fi = (0 * 8 + wn * 2 + nt) * 4 + ks;
            w1f[ks * 2 + nt] = *(const bf16x8*)((const char*)w1gF + fi * 1024 + lane * 16);
        }

    // ---- Stage A (bf16 copy) + inline LN3 stats: 8 thr/row x 16 ch ----
    {
        const int rr = tid >> 3, part = tid & 7;
        const unsigned short* src = outb + (row0 + rr) * D + part * 16;
        const uint4 v0 = *(const uint4*)(src);       // 8 bf16
        const uint4 v1 = *(const uint4*)(src + 8);   // 8 bf16
        float s = 0.f, sq = 0.f;
        const unsigned w[8] = {v0.x, v0.y, v0.z, v0.w, v1.x, v1.y, v1.z, v1.w};
        #pragma unroll
        for (int e = 0; e < 8; ++e) {
            const float lo = __builtin_bit_cast(float, w[e] << 16);
            const float hi = __builtin_bit_cast(float, w[e] & 0xffff0000u);
            s  += lo + hi;
            sq += lo * lo + hi * hi;
        }
        s  += __shfl_xor(s, 1);  s  += __shfl_xor(s, 2);  s  += __shfl_xor(s, 4);
        sq += __shfl_xor(sq, 1); sq += __shfl_xor(sq, 2); sq += __shfl_xor(sq, 4);
        if (part == 0) {
            const float mean = s * (1.0f / D);
            const float rstd = rsqrtf(sq * (1.0f / D) - mean * mean + 1e-5f);
            stats[rr] = make_float2(rstd, mean * rstd);
        }
        const int xr = (rr & 7) << 4;
        char* rowp = (char*)(At + rr * 128);
        const int cb = part * 32;                 // byte offset of 16 bf16
        *(uint4*)(rowp + ((cb     ) ^ xr)) = v0;
        *(uint4*)(rowp + ((cb + 16) ^ xr)) = v1;
    }

    // ---- preload W2 fragments for kc=0 ----
    #pragma unroll
    for (int ks = 0; ks < 4; ++ks)
        #pragma unroll
        for (int nt = 0; nt < 2; ++nt) {
            const int fi = (wn * 2 + nt) * 16 + 0 * 4 + ks;
            w2f[ks * 2 + nt] = *(const bf16x8*)((const char*)w2tF + fi * 1024 + lane * 16);
        }

    __syncthreads();

    f32x4 acc2[2][2];
    #pragma unroll
    for (int m = 0; m < 2; ++m)
        #pragma unroll
        for (int n = 0; n < 2; ++n) acc2[m][n] = (f32x4){0.f, 0.f, 0.f, 0.f};

    #pragma unroll
    for (int kc = 0; kc < 4; ++kc) {
        const int p = kc & 1;

        // ---- GEMM1-chunk ----
        {
            f32x4 acc1[2][2];
            #pragma unroll
            for (int m = 0; m < 2; ++m)
                #pragma unroll
                for (int n = 0; n < 2; ++n) acc1[m][n] = (f32x4){0.f, 0.f, 0.f, 0.f};

            #pragma unroll
            for (int ks = 0; ks < 4; ++ks) {
                bf16x8 af[2];
                #pragma unroll
                for (int mt = 0; mt < 2; ++mt) {
                    const int row = wm * 32 + mt * 16 + lr;
                    af[mt] = *(const bf16x8*)((char*)(At + row * 128) +
                              ((ks * 64 + lg * 16) ^ ((row & 7) << 4)));
                }
                #pragma unroll
                for (int mt = 0; mt < 2; ++mt)
                    #pragma unroll
                    for (int nt = 0; nt < 2; ++nt)
                        acc1[mt][nt] = MFMA16(af[mt], w1f[ks * 2 + nt], acc1[mt][nt]);
            }

            #pragma unroll
            for (int nt = 0; nt < 2; ++nt) {
                const int chl = wn * 32 + nt * 16 + lr;        // 0..127
                const float2 cc = c1c2[kc * 128 + chl];
                #pragma unroll
                for (int mt = 0; mt < 2; ++mt) {
                    #pragma unroll
                    for (int r = 0; r < 4; ++r) {
                        const int row = wm * 32 + mt * 16 + lg * 4 + r;
                        const float2 st = stats[row];
                        const float pre = st.x * acc1[mt][nt][r] - st.y * cc.x + cc.y;
                        *(unsigned short*)((char*)(hid[p] + row * 128) +
                            ((chl * 2) ^ ((row & 7) << 4))) = f2bf(fmaxf(pre, 0.f));
                    }
                }
            }
        }
        __syncthreads();

        // refill W1 for kc+1 AFTER the barrier (overlaps GEMM2)
        if (kc < 3) {
            #pragma unroll
            for (int ks = 0; ks < 4; ++ks)
                #pragma unroll
                for (int nt = 0; nt < 2; ++nt) {
                    const int fi = ((kc + 1) * 8 + wn * 2 + nt) * 4 + ks;
                    w1f[ks * 2 + nt] = *(const bf16x8*)((const char*)w1gF + fi * 1024 + lane * 16);
                }
        }

        // ---- GEMM2-chunk ----
        {
            #pragma unroll
            for (int ks = 0; ks < 4; ++ks) {
                bf16x8 hf[2];
                #pragma unroll
                for (int mt = 0; mt < 2; ++mt) {
                    const int row = wm * 32 + mt * 16 + lr;
                    hf[mt] = *(const bf16x8*)((char*)(hid[p] + row * 128) +
                              ((ks * 64 + lg * 16) ^ ((row & 7) << 4)));
                }
                #pragma unroll
                for (int mt = 0; mt < 2; ++mt)
                    #pragma unroll
                    for (int nt = 0; nt < 2; ++nt)
                        acc2[mt][nt] = MFMA16(hf[mt], w2f[ks * 2 + nt], acc2[mt][nt]);
            }
        }

        // refill W2 for kc+1 (overlaps next GEMM1)
        if (kc < 3) {
            #pragma unroll
            for (int ks = 0; ks < 4; ++ks)
                #pragma unroll
                for (int nt = 0; nt < 2; ++nt) {
                    const int fi = (wn * 2 + nt) * 16 + (kc + 1) * 4 + ks;
                    w2f[ks * 2 + nt] = *(const bf16x8*)((const char*)w2tF + fi * 1024 + lane * 16);
                }
        }
    }

    // ---- epilogue: out = bf2f(At) + acc2 + ffb2 (pure store, no RMW) ----
    #pragma unroll
    for (int nt = 0; nt < 2; ++nt) {
        const int ch = wn * 32 + nt * 16 + lr;
        const float bb = ffb2[ch];
        #pragma unroll
        for (int mt = 0; mt < 2; ++mt) {
            #pragma unroll
            for (int r = 0; r < 4; ++r) {
                const int row = wm * 32 + mt * 16 + lg * 4 + r;
                const float resid = bf2f(*(const unsigned short*)((char*)(At + row * 128) +
                                     ((ch * 2) ^ ((row & 7) << 4))));
                out[(row0 + row) * (size_t)D + ch] = resid + acc2[mt][nt][r] + bb;
            }
        }
    }
}

// ---------------------------------------------------------------------------
extern "C" void kernel_launch(void* const* d_in, const int* in_sizes, int n_in,
                              void* d_out, int out_size, void* d_ws, size_t ws_size,
                              hipStream_t stream) {
    const float* x     = (const float*)d_in[0];
    const float* m     = (const float*)d_in[1];
    const float* ln1_g = (const float*)d_in[2];
    const float* ln1_b = (const float*)d_in[3];
    const float* ln2_g = (const float*)d_in[4];
    const float* ln2_b = (const float*)d_in[5];
    const float* ln3_g = (const float*)d_in[6];
    const float* ln3_b = (const float*)d_in[7];
    const float* w1    = (const float*)d_in[8];
    const float* b1    = (const float*)d_in[9];
    const float* w2    = (const float*)d_in[10];
    const float* b2    = (const float*)d_in[11];
    const float* ffw1  = (const float*)d_in[12];
    const float* ffb1  = (const float*)d_in[13];
    const float* ffw2  = (const float*)d_in[14];
    const float* ffb2  = (const float*)d_in[15];

    float* out = (float*)d_out;

    char* wsp = (char*)d_ws;
    float*          logits = (float*)wsp;              wsp += (size_t)L*L*NH*4;   // 4.72 MB
    unsigned short* attnT  = (unsigned short*)wsp;     wsp += (size_t)NH*L*L*2;   // 2.36 MB
    unsigned short* VtT    = (unsigned short*)wsp;     wsp += (size_t)R*HD*L*2;   // 3.15 MB
    unsigned short* w1gF   = (unsigned short*)wsp;     wsp += (size_t)FF*D*2;     // 128 KB
    unsigned short* w2tF   = (unsigned short*)wsp;     wsp += (size_t)D*FF*2;     // 128 KB
    unsigned short* w1p    = (unsigned short*)wsp;     wsp += (size_t)16*D*2;     // 4 KB
    unsigned short* w2p    = (unsigned short*)wsp;     wsp += (size_t)16*D*2;     // 4 KB
    float2*         c1c2   = (float2*)wsp;             wsp += (size_t)FF*8;       // 4 KB
    unsigned short* outb   = (unsigned short*)wsp;     wsp += (size_t)R*L*D*2;    // 25.2 MB

    k_prep<<<(FF * D) / 256, 256, 0, stream>>>(w1, w2, ffw1, ffw2,
                                               ln3_g, ln3_b, ffb1,
                                               w1p, w2p, w1gF, w2tF, c1c2);

    // merged: 1176 tile pair-logit blocks + 1536 values blocks (512 threads)
    k_plv<<<NPAIRT + R * 6, 512, 0, stream>>>(x, ln1_g, ln1_b, w1p, b1, logits,
                                              m, ln2_g, ln2_b, w2p, b2, VtT);

    k_softmax<<<(L * NH) / 4, 256, 0, stream>>>(logits, attnT);

    dim3 g4(L / 128, (R * HD) / 128, NH);
    k_attn_out<<<g4, 256, 0, stream>>>(attnT, VtT, m, outb);

    k_ffn<<<(R * L) / 64, 512, 0, stream>>>(outb, w1gF, c1c2, w2tF, ffb2, out);
}